// Round 4
// baseline (210.361 us; speedup 1.0000x reference)
//
#include <hip/hip_runtime.h>

#define B 8
#define N 2048
#define D 1024
#define C 16           // chunks along i
#define LC (N / C)     // 128 rows per chunk
#define M 6            // Taylor terms
#define NBLK (B * C * 2)   // 256 fused blocks: (b, c, dhalf)
#define RECF (M * 512)     // floats per record: 6 moments x 512 cols

// ws layout (floats):
//   kq    @ 0     : 2*B*N = 32768  (k then q)
//   flags @ 32768 : 256 ints (reserve 1024 floats)
//   precs @ 33792 : NBLK*RECF = 786432 floats (~3 MB chunk-aggregate records)

// ---------------------------------------------------------------------------
// K1: k/q projections (one wave per row); block 0 also clears the flags.
__global__ __launch_bounds__(256) void k_proj(const float* __restrict__ x,
                                              const float* __restrict__ wk,
                                              const float* __restrict__ wq,
                                              float* __restrict__ kq,
                                              int* __restrict__ flags) {
    if (blockIdx.x == 0) flags[threadIdx.x] = 0;       // 256 flags

    const int wave = threadIdx.x >> 6;
    const int lane = threadIdx.x & 63;
    const int row  = blockIdx.x * 4 + wave;            // [0, B*N)
    const float4* xr  = (const float4*)(x + (size_t)row * D);
    const float4* wk4 = (const float4*)wk;
    const float4* wq4 = (const float4*)wq;
    float ak = 0.f, aq = 0.f;
#pragma unroll
    for (int t = 0; t < (D / 4) / 64; ++t) {           // 4 iterations
        float4 xv = xr[t * 64 + lane];
        float4 kv = wk4[t * 64 + lane];
        float4 qv = wq4[t * 64 + lane];
        ak += xv.x * kv.x + xv.y * kv.y + xv.z * kv.z + xv.w * kv.w;
        aq += xv.x * qv.x + xv.y * qv.y + xv.z * qv.z + xv.w * qv.w;
    }
#pragma unroll
    for (int off = 32; off > 0; off >>= 1) {
        ak += __shfl_down(ak, off, 64);
        aq += __shfl_down(aq, off, 64);
    }
    if (lane == 0) {
        kq[row] = ak;
        kq[B * N + row] = aq;
    }
}

// ---------------------------------------------------------------------------
// K2: fused moments + bounded aggregate-lookback + output.
//     block = (b, c, dh); 256 blocks <= 256 CUs -> all co-resident; a block
//     waits only on lower-c blocks of its own (b,dh) chain, and reads at most
//     15 aggregate records (no inclusive chase, no serial chain).
__global__ __launch_bounds__(256, 4) void k_fused(
    const float* __restrict__ kq, const float* __restrict__ f,
    float* __restrict__ precs, int* __restrict__ flags,
    float* __restrict__ out)
{
    const int bid   = blockIdx.x;
    const int dh    = bid & 1;
    const int c     = (bid >> 1) & (C - 1);
    const int b     = bid >> 5;
    const int chain = b * 2 + dh;                      // 0..15
    const int tid   = threadIdx.x;
    const int d     = dh * 512 + tid * 2;              // thread owns 2 d-cols

    __shared__ float sk[LC];
    __shared__ float sq[LC];
    __shared__ float sT[M];

    if (tid < 128) sk[tid]       = kq[b * N + c * LC + tid];
    else           sq[tid - 128] = kq[B * N + b * N + c * LC + (tid - 128)];
    __syncthreads();

    // ---- phase A: vector chunk moments (f streamed, coalesced float2)
    const float2* fb = (const float2*)(f + (size_t)(b * N + c * LC) * D + d);
    float2 s[M];
#pragma unroll
    for (int m = 0; m < M; ++m) s[m] = make_float2(0.f, 0.f);
#pragma unroll 8
    for (int i = 0; i < LC; ++i) {
        float2 ff = fb[i * (D / 2)];
        float  kk = sk[i];
        float  w  = (kk != 0.0f) ? 1.0f : 0.0f;
        s[0].x += w * ff.x; s[0].y += w * ff.y;
        float kp = kk;
#pragma unroll
        for (int m = 1; m < M; ++m) {
            s[m].x += kp * ff.x; s[m].y += kp * ff.y;
            kp *= kk;
        }
    }

    // ---- publish aggregate record ASAP (last chunk has no successor)
    if (c < C - 1) {
        float* rec = precs + (size_t)(chain * C + c) * RECF;
#pragma unroll
        for (int m = 0; m < M; ++m)
            ((float2*)(rec + m * 512))[tid] = s[m];
        __syncthreads();                               // drains vmcnt per wave
        if (tid == 0) {
            __threadfence();                           // device-scope release
            __hip_atomic_store(&flags[chain * C + c], 1,
                               __ATOMIC_RELAXED, __HIP_MEMORY_SCOPE_AGENT);
        }
    }

    // ---- scalar exclusive prefix over all 16 chunks (lanes 0..15, wave 0);
    //      overlaps with other waves' work; no inter-block traffic needed.
    if (tid < C) {
        float tm[M] = {0.f, 0.f, 0.f, 0.f, 0.f, 0.f};
        const float* kb = kq + b * N + tid * LC;
#pragma unroll 8
        for (int i = 0; i < LC; ++i) {
            float kk = kb[i];
            tm[0] += (kk != 0.0f) ? 1.0f : 0.0f;
            float kp = kk;
#pragma unroll
            for (int m = 1; m < M; ++m) { tm[m] += kp; kp *= kk; }
        }
#pragma unroll
        for (int m = 0; m < M; ++m) {
            float v = tm[m];
            const float orig = v;
#pragma unroll
            for (int off = 1; off < C; off <<= 1) {    // Kogge-Stone, 16 lanes
                float nv = __shfl_up(v, off, 64);
                if (tid >= off) v += nv;
            }
            if (tid == c) sT[m] = v - orig;            // exclusive prefix @ c
        }
    }

    // ---- bounded lookback: read predecessor aggregates in forward order
    float2 run[M];
#pragma unroll
    for (int m = 0; m < M; ++m) run[m] = make_float2(0.f, 0.f);

    if (c > 0) {
        if (tid < c) {                                 // lane tid spins on flag tid
            while (__hip_atomic_load(&flags[chain * C + tid],
                                     __ATOMIC_RELAXED, __HIP_MEMORY_SCOPE_AGENT) == 0)
                __builtin_amdgcn_s_sleep(2);
        }
        __syncthreads();
        // one acquire to order the record loads below
        (void)__hip_atomic_load(&flags[chain * C],
                                __ATOMIC_ACQUIRE, __HIP_MEMORY_SCOPE_AGENT);
        for (int p = 0; p < c; ++p) {
            const float* rp = precs + (size_t)(chain * C + p) * RECF;
#pragma unroll
            for (int m = 0; m < M; ++m) {
                float2 v = ((const float2*)(rp + m * 512))[tid];
                run[m].x += v.x; run[m].y += v.y;
            }
        }
    }
    __syncthreads();                                   // sT visible to all

    float t[M];
#pragma unroll
    for (int m = 0; m < M; ++m) t[m] = sT[m];

    // ---- phase C: local scan + Horner + output (f re-read is L2/L3-warm)
    float2* ob = (float2*)(out + (size_t)(b * N + c * LC) * D + d);
#pragma unroll 4
    for (int i = 0; i < LC; ++i) {
        float2 ff = fb[i * (D / 2)];
        float  kk = sk[i];
        float  qq = sq[i];
        float  w  = (kk != 0.0f) ? 1.0f : 0.0f;
        t[0] += w;
        run[0].x += w * ff.x; run[0].y += w * ff.y;
        float kp = kk;
#pragma unroll
        for (int m = 1; m < M; ++m) {
            t[m] += kp;
            run[m].x += kp * ff.x; run[m].y += kp * ff.y;
            kp *= kk;
        }
        const float cj = qq * 0.03125f;
        const float g2 = cj * 0.5f;
        const float g3 = cj * (1.0f / 3.0f);
        const float g4 = cj * 0.25f;
        const float g5 = cj * 0.2f;
        float Z = ((((t[5] * g5 + t[4]) * g4 + t[3]) * g3 + t[2]) * g2 + t[1]) * cj + t[0];
        float rz = __builtin_amdgcn_rcpf(Z);
        float2 o;
        o.x = (((((run[5].x * g5 + run[4].x) * g4 + run[3].x) * g3 + run[2].x) * g2 + run[1].x) * cj + run[0].x) * rz;
        o.y = (((((run[5].y * g5 + run[4].y) * g4 + run[3].y) * g3 + run[2].y) * g2 + run[1].y) * cj + run[0].y) * rz;
        ob[i * (D / 2)] = o;
    }
}

// ---------------------------------------------------------------------------
extern "C" void kernel_launch(void* const* d_in, const int* in_sizes, int n_in,
                              void* d_out, int out_size, void* d_ws, size_t ws_size,
                              hipStream_t stream) {
    (void)in_sizes; (void)n_in; (void)out_size; (void)ws_size;
    const float* x  = (const float*)d_in[0];
    const float* f  = (const float*)d_in[1];
    const float* wk = (const float*)d_in[2];
    const float* wq = (const float*)d_in[3];
    float* out = (float*)d_out;
    float* ws  = (float*)d_ws;

    float* kq    = ws;
    int*   flags = (int*)(ws + 32768);
    float* precs = ws + 33792;

    hipLaunchKernelGGL(k_proj,  dim3(B * N / 4), dim3(256), 0, stream, x, wk, wq, kq, flags);
    hipLaunchKernelGGL(k_fused, dim3(NBLK),      dim3(256), 0, stream, kq, f, precs, flags, out);
}